// Round 7
// baseline (942.657 us; speedup 1.0000x reference)
//
#include <hip/hip_runtime.h>
#include <hip/hip_cooperative_groups.h>
#include <cstdint>
#include <cstddef>

namespace cg = cooperative_groups;

// Problem constants
#define N_NODES 50000
#define N_EDGES 1600000
#define N_REL 8
#define N_BASIS 4
#define DIM 240
#define NEG_SLOPE 0.01f

#define CAP_S1 256     // max nodes needing layer-1 h (expected ~66)
#define CAP_DEG 128    // max in-degree of a relevant node (Poisson(32))
#define BITMAP_WORDS ((N_NODES + 31) / 32)   // 1563
#define NCH 8
#define CHUNK (DIM / NCH)  // 30
#define GRID_BLKS 1024

// ---- fixed workspace layout (256-aligned offsets, bytes) ----
#define WS_CNTS       0        // 2 ints
#define WS_DEGS       256      // CAP_S1 ints
#define WS_BITMAP     1280     // 1563 u32 (ends 7532)
#define WS_H2ACC      7680     // 2*DIM f32 (ends 9600)
#define WS_H1RAW      9728     // CAP_S1*DIM f32 (ends 255488)
#define WS_ZERO_BYTES 255488   // everything above is zeroed
#define WS_MAP        255488   // N_NODES ints (ends 455488)
#define WS_NODES      455680   // CAP_S1 ints
#define WS_ESLOT      456704   // CAP_S1*CAP_DEG u32 (ends 587776)
#define WS_Z1         587776   // CAP_S1*5*DIM f32 (ends 1816576)
#define WS_TOTAL      1816576

__device__ __forceinline__ float lrelu(float v) { return v > 0.f ? v : NEG_SLOPE * v; }

// ================= cooperative mono-kernel =================
__global__ __launch_bounds__(256, 4) void k_all(
    const float* __restrict__ x, const int* __restrict__ ei, const int* __restrict__ et,
    const float* __restrict__ comp, const float* __restrict__ basis,
    const float* __restrict__ root, const float* __restrict__ bias,
    const float* __restrict__ W1, const float* __restrict__ b1,
    const float* __restrict__ W2, const float* __restrict__ b2,
    const int* __restrict__ cip, const int* __restrict__ sip,
    float* __restrict__ out, char* __restrict__ ws) {
    cg::grid_group grid = cg::this_grid();

    int*      cnts   = (int*)(ws + WS_CNTS);
    int*      degs   = (int*)(ws + WS_DEGS);
    unsigned* bitmap = (unsigned*)(ws + WS_BITMAP);
    float*    h2acc  = (float*)(ws + WS_H2ACC);
    float*    h1raw  = (float*)(ws + WS_H1RAW);
    int*      map    = (int*)(ws + WS_MAP);
    int*      nodes  = (int*)(ws + WS_NODES);
    unsigned* eslot  = (unsigned*)(ws + WS_ESLOT);
    float*    z1     = (float*)(ws + WS_Z1);

    const float* comp2  = comp  + N_REL * N_BASIS;
    const float* basis2 = basis + (size_t)N_BASIS * DIM * DIM;
    const float* root2  = root  + (size_t)DIM * DIM;
    const float* bias2  = bias  + DIM;

    int t = threadIdx.x;
    int tid = blockIdx.x * 256 + t;
    int nth = gridDim.x * 256;

    __shared__ unsigned els[CAP_DEG];
    __shared__ float cs[N_REL * N_BASIS];
    __shared__ float zpart[8][N_BASIS][CHUNK];
    __shared__ float zc[5][CHUNK];
    __shared__ float cat[2 * DIM];
    __shared__ float part[128][2];
    __shared__ float hid[128];

    int ci = cip[0], si = sip[0];

    // ---- phase 0: zero counters/accumulators ----
    {
        int* zp = (int*)ws;
        for (int i = tid; i < WS_ZERO_BYTES / 4; i += nth) zp[i] = 0;
    }
    grid.sync();

    // ---- phase 1: mark srcs of in-edges of {ci,si}; seed ci,si ----
    if (tid == 0) {
        atomicOr(&bitmap[ci >> 5], 1u << (ci & 31));
        atomicOr(&bitmap[si >> 5], 1u << (si & 31));
    }
    for (int q = tid; q < N_EDGES / 4; q += nth) {
        int base = q * 4;
        int4 d = *reinterpret_cast<const int4*>(ei + N_EDGES + base);
        int dv[4] = {d.x, d.y, d.z, d.w};
#pragma unroll
        for (int j = 0; j < 4; j++)
            if (dv[j] == ci || dv[j] == si) {
                int src = ei[base + j];
                atomicOr(&bitmap[src >> 5], 1u << (src & 31));
            }
    }
    grid.sync();

    // ---- phase 2: compact bitmap -> slots ----
    for (int n = tid; n < N_NODES; n += nth) {
        if ((bitmap[n >> 5] >> (n & 31)) & 1u) {
            int slot = atomicAdd(&cnts[0], 1);
            if (slot < CAP_S1) { map[n] = slot; nodes[slot] = n; }
            else map[n] = -1;
        }
    }
    grid.sync();

    // ---- phase 3: slot-CSR of in-edges of marked nodes ----
    for (int q = tid; q < N_EDGES / 4; q += nth) {
        int base = q * 4;
        int4 d = *reinterpret_cast<const int4*>(ei + N_EDGES + base);
        int dv[4] = {d.x, d.y, d.z, d.w};
#pragma unroll
        for (int j = 0; j < 4; j++) {
            int dst = dv[j];
            if ((bitmap[dst >> 5] >> (dst & 31)) & 1u) {
                int slot = map[dst];
                if (slot >= 0) {
                    int idx = atomicAdd(&degs[slot], 1);
                    if (idx < CAP_DEG)
                        eslot[(size_t)slot * CAP_DEG + idx] =
                            (unsigned)ei[base + j] | ((unsigned)et[base + j] << 16);
                }
            }
        }
    }
    grid.sync();

    // ---- phase 4: layer-1 aggregation z1 ----
    int nS1 = min(cnts[0], CAP_S1);
    for (int slot = blockIdx.x; slot < nS1; slot += gridDim.x) {
        int deg = min(degs[slot], CAP_DEG);
        if (t < N_REL * N_BASIS) cs[t] = comp[t];
        if (t < deg) els[t] = eslot[(size_t)slot * CAP_DEG + t];
        __syncthreads();
        if (t < DIM) {
            float a0 = 0.f, a1 = 0.f, a2 = 0.f, a3 = 0.f;
            int base = 0;
            for (; base + 4 <= deg; base += 4) {
                float xv[4]; int ty[4];
#pragma unroll
                for (int j = 0; j < 4; j++) {
                    unsigned p = els[base + j];
                    ty[j] = (int)(p >> 16);
                    xv[j] = x[(size_t)(p & 0xFFFFu) * DIM + t];
                }
#pragma unroll
                for (int j = 0; j < 4; j++) {
                    const float* c = &cs[ty[j] * N_BASIS];
                    a0 += c[0] * xv[j]; a1 += c[1] * xv[j];
                    a2 += c[2] * xv[j]; a3 += c[3] * xv[j];
                }
            }
            for (; base < deg; base++) {
                unsigned p = els[base];
                const float* c = &cs[(p >> 16) * N_BASIS];
                float xv = x[(size_t)(p & 0xFFFFu) * DIM + t];
                a0 += c[0] * xv; a1 += c[1] * xv; a2 += c[2] * xv; a3 += c[3] * xv;
            }
            float* zp = z1 + (size_t)slot * 5 * DIM;
            zp[0 * DIM + t] = a0; zp[1 * DIM + t] = a1;
            zp[2 * DIM + t] = a2; zp[3 * DIM + t] = a3;
            zp[4 * DIM + t] = x[(size_t)nodes[slot] * DIM + t];
        }
        __syncthreads();
    }
    grid.sync();

    // ---- phase 5: layer-1 GEMM partials into h1raw ----
    for (int task = blockIdx.x; task < nS1 * NCH; task += gridDim.x) {
        int slot = task >> 3, ch = task & 7;
        int i0 = ch * CHUNK;
        if (t < 5 * CHUNK) {
            int b = t / CHUNK, ii = t % CHUNK;
            zc[b][ii] = z1[((size_t)slot * 5 + b) * DIM + i0 + ii];
        }
        __syncthreads();
        if (t < DIM) {
            float acc = 0.f;
#pragma unroll 5
            for (int ii = 0; ii < CHUNK; ii++) {
                int i = i0 + ii;
                acc += zc[0][ii] * basis[(size_t)(0 * DIM + i) * DIM + t];
                acc += zc[1][ii] * basis[(size_t)(1 * DIM + i) * DIM + t];
                acc += zc[2][ii] * basis[(size_t)(2 * DIM + i) * DIM + t];
                acc += zc[3][ii] * basis[(size_t)(3 * DIM + i) * DIM + t];
                acc += zc[4][ii] * root[(size_t)i * DIM + t];
            }
            atomicAdd(&h1raw[(size_t)slot * DIM + t], acc);
        }
        __syncthreads();
    }
    grid.sync();

    // ---- phase 6: layer-2 fused aggregate + chunk-GEMM ----
    for (int task = blockIdx.x; task < 2 * NCH; task += gridDim.x) {
        int w = task >> 3, ch = task & 7;
        int i0 = ch * CHUNK;
        int node = w ? si : ci;
        int slot = map[node];
        int deg = (slot >= 0) ? min(degs[slot], CAP_DEG) : 0;
        if (t < N_REL * N_BASIS) cs[t] = comp2[t];
        if (t < deg) els[t] = eslot[(size_t)slot * CAP_DEG + t];
        __syncthreads();
        if (t < 8 * CHUNK) {
            int e8 = t / CHUNK, d = t % CHUNK;
            float a0 = 0.f, a1 = 0.f, a2 = 0.f, a3 = 0.f;
            for (int base = 0; base < deg; base += 8) {
                int e = base + e8;
                if (e < deg) {
                    unsigned p = els[e];
                    int ss = map[p & 0xFFFFu];
                    float hv = 0.f;
                    if (ss >= 0)
                        hv = lrelu(h1raw[(size_t)ss * DIM + i0 + d] + bias[i0 + d]);
                    const float* c = &cs[(p >> 16) * N_BASIS];
                    a0 += c[0] * hv; a1 += c[1] * hv; a2 += c[2] * hv; a3 += c[3] * hv;
                }
            }
            zpart[e8][0][d] = a0; zpart[e8][1][d] = a1;
            zpart[e8][2][d] = a2; zpart[e8][3][d] = a3;
        }
        __syncthreads();
        if (t < N_BASIS * CHUNK) {
            int b = t / CHUNK, d = t % CHUNK;
            float s = 0.f;
#pragma unroll
            for (int e = 0; e < 8; e++) s += zpart[e][b][d];
            zc[b][d] = s;
        } else if (t < 5 * CHUNK) {
            int d = t - N_BASIS * CHUNK;
            zc[4][d] = (slot >= 0)
                ? lrelu(h1raw[(size_t)slot * DIM + i0 + d] + bias[i0 + d]) : 0.f;
        }
        __syncthreads();
        if (t < DIM) {
            float acc = 0.f;
#pragma unroll 5
            for (int ii = 0; ii < CHUNK; ii++) {
                int i = i0 + ii;
                acc += zc[0][ii] * basis2[(size_t)(0 * DIM + i) * DIM + t];
                acc += zc[1][ii] * basis2[(size_t)(1 * DIM + i) * DIM + t];
                acc += zc[2][ii] * basis2[(size_t)(2 * DIM + i) * DIM + t];
                acc += zc[3][ii] * basis2[(size_t)(3 * DIM + i) * DIM + t];
                acc += zc[4][ii] * root2[(size_t)i * DIM + t];
            }
            atomicAdd(&h2acc[w * DIM + t], acc);
        }
        __syncthreads();
    }
    grid.sync();

    // ---- phase 7: head MLP (block 0) ----
    if (blockIdx.x == 0) {
        if (t < DIM) {
            float hc = h2acc[t] + bias2[t];
            float hs = h2acc[DIM + t] + bias2[t];
            cat[t] = fabsf(hs - hc);
            cat[DIM + t] = hs * hc;
        }
        __syncthreads();
        {
            int r = t >> 1, q = t & 1;
            const float4* wr = reinterpret_cast<const float4*>(W1 + (size_t)r * 2 * DIM) + q * 60;
            const float4* cq = reinterpret_cast<const float4*>(cat) + q * 60;
            float acc = 0.f;
#pragma unroll 6
            for (int k = 0; k < 60; k++) {
                float4 wv = wr[k], cv = cq[k];
                acc += wv.x * cv.x + wv.y * cv.y + wv.z * cv.z + wv.w * cv.w;
            }
            part[r][q] = acc;
        }
        __syncthreads();
        if ((t & 1) == 0) {
            int r = t >> 1;
            float s = part[r][0] + part[r][1] + b1[r];
            hid[r] = lrelu(s) * W2[r];
        }
        __syncthreads();
        if (t < 64) {
            float v = hid[t] + hid[t + 64];
            for (int o = 32; o > 0; o >>= 1) v += __shfl_down(v, o);
            if (t == 0) out[0] = b2[0] + v;
        }
    }
}

// ================= fallback multi-kernel path (round-4 proven) =================
__global__ __launch_bounds__(256) void k_pass1(const int* __restrict__ ei,
                                               const int* __restrict__ cip,
                                               const int* __restrict__ sip,
                                               unsigned* __restrict__ bitmap) {
    int base = (blockIdx.x * 256 + threadIdx.x) * 4;
    int ci = cip[0], si = sip[0];
    if (blockIdx.x == 0 && threadIdx.x == 0) {
        atomicOr(&bitmap[ci >> 5], 1u << (ci & 31));
        atomicOr(&bitmap[si >> 5], 1u << (si & 31));
    }
    if (base < N_EDGES) {
        int4 d = *reinterpret_cast<const int4*>(ei + N_EDGES + base);
        int dv[4] = {d.x, d.y, d.z, d.w};
#pragma unroll
        for (int j = 0; j < 4; j++)
            if (dv[j] == ci || dv[j] == si) {
                int src = ei[base + j];
                atomicOr(&bitmap[src >> 5], 1u << (src & 31));
            }
    }
}

__global__ __launch_bounds__(256) void k_compact(const unsigned* __restrict__ bitmap,
                                                 int* __restrict__ map,
                                                 int* __restrict__ nodes,
                                                 int* __restrict__ cnts) {
    int n = blockIdx.x * 256 + threadIdx.x;
    if (n < N_NODES && ((bitmap[n >> 5] >> (n & 31)) & 1u)) {
        int slot = atomicAdd(&cnts[0], 1);
        if (slot < CAP_S1) { map[n] = slot; nodes[slot] = n; }
        else map[n] = -1;
    }
}

__global__ __launch_bounds__(256) void k_pass2(const int* __restrict__ ei,
                                               const int* __restrict__ et,
                                               const unsigned* __restrict__ bitmap,
                                               const int* __restrict__ map,
                                               int* __restrict__ degs,
                                               unsigned* __restrict__ eslot) {
    int base = (blockIdx.x * 256 + threadIdx.x) * 4;
    if (base < N_EDGES) {
        int4 d = *reinterpret_cast<const int4*>(ei + N_EDGES + base);
        int dv[4] = {d.x, d.y, d.z, d.w};
#pragma unroll
        for (int j = 0; j < 4; j++) {
            int dst = dv[j];
            if ((bitmap[dst >> 5] >> (dst & 31)) & 1u) {
                int slot = map[dst];
                if (slot >= 0) {
                    int idx = atomicAdd(&degs[slot], 1);
                    if (idx < CAP_DEG)
                        eslot[(size_t)slot * CAP_DEG + idx] =
                            (unsigned)ei[base + j] | ((unsigned)et[base + j] << 16);
                }
            }
        }
    }
}

__global__ __launch_bounds__(256) void k_z1(const float* __restrict__ x,
                                            const unsigned* __restrict__ eslot,
                                            const int* __restrict__ degs,
                                            const int* __restrict__ nodes,
                                            const int* __restrict__ cnts,
                                            const float* __restrict__ compL,
                                            float* __restrict__ z1) {
    int slot = blockIdx.x;
    if (slot >= min(cnts[0], CAP_S1)) return;
    int t = threadIdx.x;
    __shared__ unsigned els[CAP_DEG];
    __shared__ float cs[N_REL * N_BASIS];
    int deg = min(degs[slot], CAP_DEG);
    if (t < N_REL * N_BASIS) cs[t] = compL[t];
    if (t < deg) els[t] = eslot[(size_t)slot * CAP_DEG + t];
    __syncthreads();
    if (t < DIM) {
        float a0 = 0.f, a1 = 0.f, a2 = 0.f, a3 = 0.f;
        int base = 0;
        for (; base + 4 <= deg; base += 4) {
            float xv[4]; int ty[4];
#pragma unroll
            for (int j = 0; j < 4; j++) {
                unsigned p = els[base + j];
                ty[j] = (int)(p >> 16);
                xv[j] = x[(size_t)(p & 0xFFFFu) * DIM + t];
            }
#pragma unroll
            for (int j = 0; j < 4; j++) {
                const float* c = &cs[ty[j] * N_BASIS];
                a0 += c[0] * xv[j]; a1 += c[1] * xv[j];
                a2 += c[2] * xv[j]; a3 += c[3] * xv[j];
            }
        }
        for (; base < deg; base++) {
            unsigned p = els[base];
            const float* c = &cs[(p >> 16) * N_BASIS];
            float xv = x[(size_t)(p & 0xFFFFu) * DIM + t];
            a0 += c[0] * xv; a1 += c[1] * xv; a2 += c[2] * xv; a3 += c[3] * xv;
        }
        float* zp = z1 + (size_t)slot * 5 * DIM;
        zp[0 * DIM + t] = a0; zp[1 * DIM + t] = a1;
        zp[2 * DIM + t] = a2; zp[3 * DIM + t] = a3;
        zp[4 * DIM + t] = x[(size_t)nodes[slot] * DIM + t];
    }
}

__global__ __launch_bounds__(256) void k_hgemm(const float* __restrict__ z1,
                                               const int* __restrict__ cnts,
                                               const float* __restrict__ basisL,
                                               const float* __restrict__ rootL,
                                               float* __restrict__ h1raw) {
    int slot = blockIdx.x;
    if (slot >= min(cnts[0], CAP_S1)) return;
    int ch = blockIdx.y;
    int i0 = ch * CHUNK;
    int t = threadIdx.x;
    __shared__ float zcs[5][CHUNK];
    if (t < 5 * CHUNK) {
        int b = t / CHUNK, ii = t % CHUNK;
        zcs[b][ii] = z1[((size_t)slot * 5 + b) * DIM + i0 + ii];
    }
    __syncthreads();
    if (t < DIM) {
        float acc = 0.f;
#pragma unroll 5
        for (int ii = 0; ii < CHUNK; ii++) {
            int i = i0 + ii;
            acc += zcs[0][ii] * basisL[(size_t)(0 * DIM + i) * DIM + t];
            acc += zcs[1][ii] * basisL[(size_t)(1 * DIM + i) * DIM + t];
            acc += zcs[2][ii] * basisL[(size_t)(2 * DIM + i) * DIM + t];
            acc += zcs[3][ii] * basisL[(size_t)(3 * DIM + i) * DIM + t];
            acc += zcs[4][ii] * rootL[(size_t)i * DIM + t];
        }
        atomicAdd(&h1raw[(size_t)slot * DIM + t], acc);
    }
}

__global__ __launch_bounds__(256) void k_zh2(const float* __restrict__ h1raw,
                                             const unsigned* __restrict__ eslot,
                                             const int* __restrict__ degs,
                                             const int* __restrict__ map,
                                             const float* __restrict__ comp2,
                                             const float* __restrict__ bias1,
                                             const float* __restrict__ basis2,
                                             const float* __restrict__ root2,
                                             const int* __restrict__ cip,
                                             const int* __restrict__ sip,
                                             float* __restrict__ h2acc) {
    int w = blockIdx.x, ch = blockIdx.y;
    int i0 = ch * CHUNK;
    int t = threadIdx.x;
    __shared__ unsigned els[CAP_DEG];
    __shared__ float cs[N_REL * N_BASIS];
    __shared__ float zpart[8][N_BASIS][CHUNK];
    __shared__ float zcs[5][CHUNK];
    int node = w ? sip[0] : cip[0];
    int slot = map[node];
    int deg = (slot >= 0) ? min(degs[slot], CAP_DEG) : 0;
    if (t < N_REL * N_BASIS) cs[t] = comp2[t];
    if (t < deg) els[t] = eslot[(size_t)slot * CAP_DEG + t];
    __syncthreads();
    if (t < 8 * CHUNK) {
        int e8 = t / CHUNK, d = t % CHUNK;
        float a0 = 0.f, a1 = 0.f, a2 = 0.f, a3 = 0.f;
        for (int base = 0; base < deg; base += 8) {
            int e = base + e8;
            if (e < deg) {
                unsigned p = els[e];
                int ss = map[p & 0xFFFFu];
                float hv = 0.f;
                if (ss >= 0) hv = lrelu(h1raw[(size_t)ss * DIM + i0 + d] + bias1[i0 + d]);
                const float* c = &cs[(p >> 16) * N_BASIS];
                a0 += c[0] * hv; a1 += c[1] * hv; a2 += c[2] * hv; a3 += c[3] * hv;
            }
        }
        zpart[e8][0][d] = a0; zpart[e8][1][d] = a1;
        zpart[e8][2][d] = a2; zpart[e8][3][d] = a3;
    }
    __syncthreads();
    if (t < N_BASIS * CHUNK) {
        int b = t / CHUNK, d = t % CHUNK;
        float s = 0.f;
#pragma unroll
        for (int e = 0; e < 8; e++) s += zpart[e][b][d];
        zcs[b][d] = s;
    } else if (t < 5 * CHUNK) {
        int d = t - N_BASIS * CHUNK;
        zcs[4][d] = (slot >= 0) ? lrelu(h1raw[(size_t)slot * DIM + i0 + d] + bias1[i0 + d]) : 0.f;
    }
    __syncthreads();
    if (t < DIM) {
        float acc = 0.f;
#pragma unroll 5
        for (int ii = 0; ii < CHUNK; ii++) {
            int i = i0 + ii;
            acc += zcs[0][ii] * basis2[(size_t)(0 * DIM + i) * DIM + t];
            acc += zcs[1][ii] * basis2[(size_t)(1 * DIM + i) * DIM + t];
            acc += zcs[2][ii] * basis2[(size_t)(2 * DIM + i) * DIM + t];
            acc += zcs[3][ii] * basis2[(size_t)(3 * DIM + i) * DIM + t];
            acc += zcs[4][ii] * root2[(size_t)i * DIM + t];
        }
        atomicAdd(&h2acc[w * DIM + t], acc);
    }
}

__global__ __launch_bounds__(512) void k_head(const float* __restrict__ h2acc,
                                              const float* __restrict__ bias2,
                                              const float* __restrict__ W1,
                                              const float* __restrict__ b1,
                                              const float* __restrict__ W2,
                                              const float* __restrict__ b2,
                                              float* __restrict__ out) {
    __shared__ float cat[2 * DIM];
    __shared__ float part[128][4];
    __shared__ float hid[128];
    int t = threadIdx.x;
    if (t < DIM) {
        float hc = h2acc[t] + bias2[t];
        float hs = h2acc[DIM + t] + bias2[t];
        cat[t] = fabsf(hs - hc);
        cat[DIM + t] = hs * hc;
    }
    __syncthreads();
    int r = t >> 2, q = t & 3;
    const float4* wr = reinterpret_cast<const float4*>(W1 + (size_t)r * 2 * DIM) + q * 30;
    const float4* cq = reinterpret_cast<const float4*>(cat) + q * 30;
    float acc = 0.f;
#pragma unroll 6
    for (int k = 0; k < 30; k++) {
        float4 wv = wr[k];
        float4 cv = cq[k];
        acc += wv.x * cv.x + wv.y * cv.y + wv.z * cv.z + wv.w * cv.w;
    }
    part[r][q] = acc;
    __syncthreads();
    if (q == 0) {
        float s = part[r][0] + part[r][1] + part[r][2] + part[r][3] + b1[r];
        hid[r] = lrelu(s) * W2[r];
    }
    __syncthreads();
    if (t < 64) {
        float v = hid[t] + hid[t + 64];
        for (int o = 32; o > 0; o >>= 1) v += __shfl_down(v, o);
        if (t == 0) out[0] = b2[0] + v;
    }
}

// ================= launch =================
extern "C" void kernel_launch(void* const* d_in, const int* in_sizes, int n_in,
                              void* d_out, int out_size, void* d_ws, size_t ws_size,
                              hipStream_t stream) {
    const float* x     = (const float*)d_in[0];
    const int*   ei    = (const int*)d_in[1];
    const int*   et    = (const int*)d_in[2];
    const float* comp  = (const float*)d_in[3];
    const float* basis = (const float*)d_in[4];
    const float* root  = (const float*)d_in[5];
    const float* bias  = (const float*)d_in[6];
    const float* W1    = (const float*)d_in[7];
    const float* b1    = (const float*)d_in[8];
    const float* W2    = (const float*)d_in[9];
    const float* b2    = (const float*)d_in[10];
    const int*   cip   = (const int*)d_in[11];
    const int*   sip   = (const int*)d_in[12];
    float* out = (float*)d_out;
    (void)n_in; (void)in_sizes; (void)out_size;

    char* ws = (char*)d_ws;
    if (ws_size < WS_TOTAL) return;

    // ---- preferred: single cooperative dispatch ----
    void* args[] = {(void*)&x, (void*)&ei, (void*)&et, (void*)&comp, (void*)&basis,
                    (void*)&root, (void*)&bias, (void*)&W1, (void*)&b1, (void*)&W2,
                    (void*)&b2, (void*)&cip, (void*)&sip, (void*)&out, (void*)&ws};
    hipError_t cerr = hipLaunchCooperativeKernel((const void*)k_all, dim3(GRID_BLKS),
                                                 dim3(256), args, 0, stream);
    if (cerr == hipSuccess) return;

    // ---- fallback: proven multi-kernel path, same workspace layout ----
    int*      cnts   = (int*)(ws + WS_CNTS);
    int*      degs   = (int*)(ws + WS_DEGS);
    unsigned* bitmap = (unsigned*)(ws + WS_BITMAP);
    float*    h2acc  = (float*)(ws + WS_H2ACC);
    float*    h1raw  = (float*)(ws + WS_H1RAW);
    int*      map    = (int*)(ws + WS_MAP);
    int*      nodes  = (int*)(ws + WS_NODES);
    unsigned* eslot  = (unsigned*)(ws + WS_ESLOT);
    float*    z1     = (float*)(ws + WS_Z1);

    hipMemsetAsync(ws, 0, WS_ZERO_BYTES, stream);

    const float* comp2  = comp  + N_REL * N_BASIS;
    const float* basis2 = basis + (size_t)N_BASIS * DIM * DIM;
    const float* root2  = root  + (size_t)DIM * DIM;
    const float* bias2  = bias  + DIM;

    int egrid4 = (N_EDGES / 4 + 255) / 256;
    k_pass1<<<egrid4, 256, 0, stream>>>(ei, cip, sip, bitmap);
    k_compact<<<(N_NODES + 255) / 256, 256, 0, stream>>>(bitmap, map, nodes, cnts);
    k_pass2<<<egrid4, 256, 0, stream>>>(ei, et, bitmap, map, degs, eslot);
    k_z1<<<CAP_S1, 256, 0, stream>>>(x, eslot, degs, nodes, cnts, comp, z1);
    k_hgemm<<<dim3(CAP_S1, NCH), 256, 0, stream>>>(z1, cnts, basis, root, h1raw);
    k_zh2<<<dim3(2, NCH), 256, 0, stream>>>(h1raw, eslot, degs, map, comp2, bias,
                                            basis2, root2, cip, sip, h2acc);
    k_head<<<1, 512, 0, stream>>>(h2acc, bias2, W1, b1, W2, b2, out);
}

// Round 8
// 168.399 us; speedup vs baseline: 5.5978x; 5.5978x over previous
//
#include <hip/hip_runtime.h>
#include <cstdint>
#include <cstddef>

// Problem constants
#define N_NODES 50000
#define N_EDGES 1600000
#define N_REL 8
#define N_BASIS 4
#define DIM 240
#define NEG_SLOPE 0.01f

#define CAP_S1 256     // max nodes needing layer-1 h (expected ~66)
#define CAP_DEG 128    // max in-degree of a relevant node (Poisson(32))
#define NCH 8
#define CHUNK (DIM / NCH)  // 30 output columns per block

// ---- workspace layout (bytes, 256-aligned) ----
#define WS_CNT    0                         // 1 int (slot counter)
#define WS_DONE   8                         // 1 int (last-block counter)
#define WS_DEGS   256                       // CAP_S1 ints        (ends 1280)
#define WS_MAP    1280                      // N_NODES ints       (ends 201280)
#define WS_NODES  201344                    // CAP_S1 ints        (ends 202368)
#define WS_ESLOT  202496                    // CAP_S1*CAP_DEG u32 (ends 333568)
#define WS_H1C    333568                    // CAP_S1*DIM f32     (ends 579328)
#define WS_H2     579328                    // 2*DIM f32          (ends 581248)
#define WS_TOTAL  581248

__device__ __forceinline__ float lrelu(float v) { return v > 0.f ? v : NEG_SLOPE * v; }

// ---- 1. init: small counters + map=-1 (no reliance on ws poison value) ----
__global__ __launch_bounds__(256) void k_init(int* __restrict__ cnt,
                                              int* __restrict__ done,
                                              int* __restrict__ degs,
                                              int* __restrict__ map) {
    int t = blockIdx.x * 256 + threadIdx.x;
    int nth = gridDim.x * 256;
    for (int n = t; n < N_NODES; n += nth) map[n] = -1;
    for (int i = t; i < CAP_S1; i += nth) degs[i] = 0;
    if (t == 0) { cnt[0] = 0; done[0] = 0; }
}

// ---- 2. mark + slot-assign in one pass (CAS claim) ----
__device__ __forceinline__ void claim_node(int n, int* map, int* nodes, int* cnt) {
    int old = atomicCAS(&map[n], -1, -2);
    if (old == -1) {
        int s = atomicAdd(cnt, 1);
        if (s < CAP_S1) { nodes[s] = n; map[n] = s; }
        else map[n] = -1;  // overflow: leave unmarked
    }
}

__global__ __launch_bounds__(256) void k_mark(const int* __restrict__ ei,
                                              const int* __restrict__ cip,
                                              const int* __restrict__ sip,
                                              int* __restrict__ map,
                                              int* __restrict__ nodes,
                                              int* __restrict__ cnt) {
    int base = (blockIdx.x * 256 + threadIdx.x) * 4;
    int ci = cip[0], si = sip[0];
    if (blockIdx.x == 0 && threadIdx.x < 2)
        claim_node(threadIdx.x ? si : ci, map, nodes, cnt);
    if (base < N_EDGES) {  // N_EDGES % 4 == 0
        int4 d = *reinterpret_cast<const int4*>(ei + N_EDGES + base);
        int dv[4] = {d.x, d.y, d.z, d.w};
#pragma unroll
        for (int j = 0; j < 4; j++)
            if (dv[j] == ci || dv[j] == si)
                claim_node(ei[base + j], map, nodes, cnt);
    }
}

// ---- 3. slot-CSR of in-edges of marked nodes ----
__global__ __launch_bounds__(256) void k_csr(const int* __restrict__ ei,
                                             const int* __restrict__ et,
                                             const int* __restrict__ map,
                                             int* __restrict__ degs,
                                             unsigned* __restrict__ eslot) {
    int base = (blockIdx.x * 256 + threadIdx.x) * 4;
    if (base < N_EDGES) {
        int4 d = *reinterpret_cast<const int4*>(ei + N_EDGES + base);
        int dv[4] = {d.x, d.y, d.z, d.w};
#pragma unroll
        for (int j = 0; j < 4; j++) {
            int m = map[dv[j]];
            if (m >= 0) {
                int idx = atomicAdd(&degs[m], 1);
                if (idx < CAP_DEG)
                    eslot[(size_t)m * CAP_DEG + idx] =
                        (unsigned)ei[base + j] | ((unsigned)et[base + j] << 16);
            }
        }
    }
}

// ---- 4. layer-1 fused: aggregate z (all i) + output-column-chunk GEMM ----
// block (slot, jch): writes h1c[slot][jch*30 .. +30) complete (bias + lrelu applied).
// No atomics, no pre-zeroed output.
__global__ __launch_bounds__(256) void k_zh1(const float* __restrict__ x,
                                             const unsigned* __restrict__ eslot,
                                             const int* __restrict__ degs,
                                             const int* __restrict__ nodes,
                                             const int* __restrict__ cnt,
                                             const float* __restrict__ comp,
                                             const float* __restrict__ basis,
                                             const float* __restrict__ root,
                                             const float* __restrict__ bias,
                                             float* __restrict__ h1c) {
    int slot = blockIdx.x;
    if (slot >= min(cnt[0], CAP_S1)) return;
    int j0 = blockIdx.y * CHUNK;
    int t = threadIdx.x;
    __shared__ float zs[5][DIM];
    __shared__ unsigned els[CAP_DEG];
    __shared__ float cs[N_REL * N_BASIS];
    __shared__ float red[NCH][CHUNK];
    int deg = min(degs[slot], CAP_DEG);
    if (t < N_REL * N_BASIS) cs[t] = comp[t];
    if (t < deg) els[t] = eslot[(size_t)slot * CAP_DEG + t];
    __syncthreads();
    if (t < DIM) {
        float a0 = 0.f, a1 = 0.f, a2 = 0.f, a3 = 0.f;
        int base = 0;
        for (; base + 4 <= deg; base += 4) {
            float xv[4]; int ty[4];
#pragma unroll
            for (int j = 0; j < 4; j++) {
                unsigned p = els[base + j];
                ty[j] = (int)(p >> 16);
                xv[j] = x[(size_t)(p & 0xFFFFu) * DIM + t];
            }
#pragma unroll
            for (int j = 0; j < 4; j++) {
                const float* c = &cs[ty[j] * N_BASIS];
                a0 += c[0] * xv[j]; a1 += c[1] * xv[j];
                a2 += c[2] * xv[j]; a3 += c[3] * xv[j];
            }
        }
        for (; base < deg; base++) {
            unsigned p = els[base];
            const float* c = &cs[(p >> 16) * N_BASIS];
            float xv = x[(size_t)(p & 0xFFFFu) * DIM + t];
            a0 += c[0] * xv; a1 += c[1] * xv; a2 += c[2] * xv; a3 += c[3] * xv;
        }
        zs[0][t] = a0; zs[1][t] = a1; zs[2][t] = a2; zs[3][t] = a3;
        zs[4][t] = x[(size_t)nodes[slot] * DIM + t];
    }
    __syncthreads();
    // GEMM over full i for this j-chunk: thread = (j, ipart)
    if (t < DIM) {
        int j = t % CHUNK, ip = t / CHUNK;   // 30 x 8
        float acc = 0.f;
#pragma unroll 6
        for (int ii = 0; ii < CHUNK; ii++) {
            int i = ip * CHUNK + ii;
            int col = j0 + j;
            acc += zs[0][i] * basis[(size_t)(0 * DIM + i) * DIM + col];
            acc += zs[1][i] * basis[(size_t)(1 * DIM + i) * DIM + col];
            acc += zs[2][i] * basis[(size_t)(2 * DIM + i) * DIM + col];
            acc += zs[3][i] * basis[(size_t)(3 * DIM + i) * DIM + col];
            acc += zs[4][i] * root[(size_t)i * DIM + col];
        }
        red[ip][j] = acc;
    }
    __syncthreads();
    if (t < CHUNK) {
        float s = 0.f;
#pragma unroll
        for (int ip = 0; ip < NCH; ip++) s += red[ip][t];
        s += bias[j0 + t];
        h1c[(size_t)slot * DIM + j0 + t] = lrelu(s);   // layer-0 activation folded in
    }
}

// ---- 5. layer-2 fused + last-block MLP head ----
__global__ __launch_bounds__(256) void k_zh2head(const float* __restrict__ h1c,
                                                 const unsigned* __restrict__ eslot,
                                                 const int* __restrict__ degs,
                                                 const int* __restrict__ map,
                                                 const float* __restrict__ comp2,
                                                 const float* __restrict__ basis2,
                                                 const float* __restrict__ root2,
                                                 const float* __restrict__ bias2,
                                                 const float* __restrict__ W1,
                                                 const float* __restrict__ b1,
                                                 const float* __restrict__ W2,
                                                 const float* __restrict__ b2,
                                                 const int* __restrict__ cip,
                                                 const int* __restrict__ sip,
                                                 float* __restrict__ h2,
                                                 int* __restrict__ done,
                                                 float* __restrict__ out) {
    int bi = blockIdx.x;           // 0..15
    int w = bi >> 3, j0 = (bi & 7) * CHUNK;
    int t = threadIdx.x;
    __shared__ float zs[5][DIM];
    __shared__ unsigned els[CAP_DEG];
    __shared__ float cs[N_REL * N_BASIS];
    __shared__ float red[NCH][CHUNK];
    __shared__ int lastflag;
    int node = w ? sip[0] : cip[0];
    int slot = map[node];
    int deg = (slot >= 0) ? min(degs[slot], CAP_DEG) : 0;
    if (t < N_REL * N_BASIS) cs[t] = comp2[t];
    if (t < deg) els[t] = eslot[(size_t)slot * CAP_DEG + t];
    __syncthreads();
    if (t < DIM) {
        float a0 = 0.f, a1 = 0.f, a2 = 0.f, a3 = 0.f;
        for (int e = 0; e < deg; e++) {
            unsigned p = els[e];
            int ss = map[p & 0xFFFFu];
            if (ss >= 0) {
                float hv = h1c[(size_t)ss * DIM + t];   // already activated
                const float* c = &cs[(p >> 16) * N_BASIS];
                a0 += c[0] * hv; a1 += c[1] * hv; a2 += c[2] * hv; a3 += c[3] * hv;
            }
        }
        zs[0][t] = a0; zs[1][t] = a1; zs[2][t] = a2; zs[3][t] = a3;
        zs[4][t] = (slot >= 0) ? h1c[(size_t)slot * DIM + t] : 0.f;
    }
    __syncthreads();
    if (t < DIM) {
        int j = t % CHUNK, ip = t / CHUNK;
        float acc = 0.f;
#pragma unroll 6
        for (int ii = 0; ii < CHUNK; ii++) {
            int i = ip * CHUNK + ii;
            int col = j0 + j;
            acc += zs[0][i] * basis2[(size_t)(0 * DIM + i) * DIM + col];
            acc += zs[1][i] * basis2[(size_t)(1 * DIM + i) * DIM + col];
            acc += zs[2][i] * basis2[(size_t)(2 * DIM + i) * DIM + col];
            acc += zs[3][i] * basis2[(size_t)(3 * DIM + i) * DIM + col];
            acc += zs[4][i] * root2[(size_t)i * DIM + col];
        }
        red[ip][j] = acc;
    }
    __syncthreads();
    if (t < CHUNK) {
        float s = 0.f;
#pragma unroll
        for (int ip = 0; ip < NCH; ip++) s += red[ip][t];
        h2[w * DIM + j0 + t] = s + bias2[j0 + t];   // last layer: no relu
    }
    // ---- last-block gate (device-scope; cheap, unlike grid.sync) ----
    __threadfence();
    __syncthreads();
    if (t == 0) lastflag = (atomicAdd(done, 1) == 15) ? 1 : 0;
    __syncthreads();
    if (!lastflag) return;
    __threadfence();  // acquire all h2 writes

    // ---- MLP head ----
    __shared__ float cat[2 * DIM];
    __shared__ float part[128][2];
    __shared__ float hid[128];
    if (t < DIM) {
        float hc = h2[t];
        float hs = h2[DIM + t];
        cat[t] = fabsf(hs - hc);
        cat[DIM + t] = hs * hc;
    }
    __syncthreads();
    {
        int r = t >> 1, q = t & 1;
        const float4* wr = reinterpret_cast<const float4*>(W1 + (size_t)r * 2 * DIM) + q * 60;
        const float4* cq = reinterpret_cast<const float4*>(cat) + q * 60;
        float acc = 0.f;
#pragma unroll 6
        for (int k = 0; k < 60; k++) {
            float4 wv = wr[k], cv = cq[k];
            acc += wv.x * cv.x + wv.y * cv.y + wv.z * cv.z + wv.w * cv.w;
        }
        part[r][q] = acc;
    }
    __syncthreads();
    if ((t & 1) == 0) {
        int r = t >> 1;
        float s = part[r][0] + part[r][1] + b1[r];
        hid[r] = lrelu(s) * W2[r];
    }
    __syncthreads();
    if (t < 64) {
        float v = hid[t] + hid[t + 64];
        for (int o = 32; o > 0; o >>= 1) v += __shfl_down(v, o);
        if (t == 0) out[0] = b2[0] + v;
    }
}

// ================= launch: 5 plain dispatches, no memset, no cooperative =================
extern "C" void kernel_launch(void* const* d_in, const int* in_sizes, int n_in,
                              void* d_out, int out_size, void* d_ws, size_t ws_size,
                              hipStream_t stream) {
    const float* x     = (const float*)d_in[0];
    const int*   ei    = (const int*)d_in[1];
    const int*   et    = (const int*)d_in[2];
    const float* comp  = (const float*)d_in[3];
    const float* basis = (const float*)d_in[4];
    const float* root  = (const float*)d_in[5];
    const float* bias  = (const float*)d_in[6];
    const float* W1    = (const float*)d_in[7];
    const float* b1    = (const float*)d_in[8];
    const float* W2    = (const float*)d_in[9];
    const float* b2    = (const float*)d_in[10];
    const int*   cip   = (const int*)d_in[11];
    const int*   sip   = (const int*)d_in[12];
    float* out = (float*)d_out;
    (void)n_in; (void)in_sizes; (void)out_size;

    char* ws = (char*)d_ws;
    if (ws_size < WS_TOTAL) return;

    int*      cnt   = (int*)(ws + WS_CNT);
    int*      done  = (int*)(ws + WS_DONE);
    int*      degs  = (int*)(ws + WS_DEGS);
    int*      map   = (int*)(ws + WS_MAP);
    int*      nodes = (int*)(ws + WS_NODES);
    unsigned* eslot = (unsigned*)(ws + WS_ESLOT);
    float*    h1c   = (float*)(ws + WS_H1C);
    float*    h2    = (float*)(ws + WS_H2);

    const float* comp2  = comp  + N_REL * N_BASIS;
    const float* basis2 = basis + (size_t)N_BASIS * DIM * DIM;
    const float* root2  = root  + (size_t)DIM * DIM;
    const float* bias2  = bias  + DIM;

    int egrid4 = (N_EDGES / 4 + 255) / 256;  // 1563

    k_init<<<256, 256, 0, stream>>>(cnt, done, degs, map);
    k_mark<<<egrid4, 256, 0, stream>>>(ei, cip, sip, map, nodes, cnt);
    k_csr<<<egrid4, 256, 0, stream>>>(ei, et, map, degs, eslot);
    k_zh1<<<dim3(CAP_S1, NCH), 256, 0, stream>>>(x, eslot, degs, nodes, cnt,
                                                 comp, basis, root, bias, h1c);
    k_zh2head<<<16, 256, 0, stream>>>(h1c, eslot, degs, map, comp2, basis2, root2,
                                      bias2, W1, b1, W2, b2, cip, sip, h2, done, out);
}

// Round 9
// 165.460 us; speedup vs baseline: 5.6972x; 1.0178x over previous
//
#include <hip/hip_runtime.h>
#include <cstdint>
#include <cstddef>

// Problem constants
#define N_NODES 50000
#define N_EDGES 1600000
#define N_REL 8
#define N_BASIS 4
#define DIM 240
#define NEG_SLOPE 0.01f

#define CAP_S1 256     // max nodes needing layer-1 h (expected ~66)
#define CAP_DEG 128    // max in-degree of a relevant node (Poisson(32))
#define BITMAP_WORDS ((N_NODES + 31) / 32)   // 1563 u32 = 6.25 KB (L1-resident)
#define NCH 8
#define CHUNK (DIM / NCH)  // 30 output columns per block

// ---- workspace layout (bytes, 256-aligned) ----
#define WS_CNT    0                         // 1 int (slot counter)
#define WS_DONE   8                         // 1 int (last-block counter)
#define WS_DEGS   256                       // CAP_S1 ints        (ends 1280)
#define WS_BITMAP 1280                      // 1563 u32           (ends 7532)
#define WS_MAP    7680                      // N_NODES ints       (ends 207680)
#define WS_NODES  207872                    // CAP_S1 ints        (ends 208896)
#define WS_ESLOT  209152                    // CAP_S1*CAP_DEG u32 (ends 340224)
#define WS_H1C    340224                    // CAP_S1*DIM f32     (ends 585984)
#define WS_H2     585984                    // 2*DIM f32          (ends 587904)
#define WS_TOTAL  587904

__device__ __forceinline__ float lrelu(float v) { return v > 0.f ? v : NEG_SLOPE * v; }

// ---- 1. init: counters + map=-1 + bitmap=0 ----
__global__ __launch_bounds__(256) void k_init(int* __restrict__ cnt,
                                              int* __restrict__ done,
                                              int* __restrict__ degs,
                                              int* __restrict__ map,
                                              unsigned* __restrict__ bitmap) {
    int t = blockIdx.x * 256 + threadIdx.x;
    int nth = gridDim.x * 256;
    for (int n = t; n < N_NODES; n += nth) map[n] = -1;
    for (int i = t; i < BITMAP_WORDS; i += nth) bitmap[i] = 0u;
    for (int i = t; i < CAP_S1; i += nth) degs[i] = 0;
    if (t == 0) { cnt[0] = 0; done[0] = 0; }
}

// ---- 2. mark + slot-assign in one pass (CAS claim); sets bitmap bit on success ----
__device__ __forceinline__ void claim_node(int n, int* map, int* nodes, int* cnt,
                                           unsigned* bitmap) {
    int old = atomicCAS(&map[n], -1, -2);
    if (old == -1) {
        int s = atomicAdd(cnt, 1);
        if (s < CAP_S1) {
            nodes[s] = n;
            map[n] = s;
            atomicOr(&bitmap[n >> 5], 1u << (n & 31));
        } else {
            map[n] = -1;  // overflow: leave unmarked, bit stays clear
        }
    }
}

__global__ __launch_bounds__(256) void k_mark(const int* __restrict__ ei,
                                              const int* __restrict__ cip,
                                              const int* __restrict__ sip,
                                              int* __restrict__ map,
                                              int* __restrict__ nodes,
                                              int* __restrict__ cnt,
                                              unsigned* __restrict__ bitmap) {
    int base = (blockIdx.x * 256 + threadIdx.x) * 4;
    int ci = cip[0], si = sip[0];
    if (blockIdx.x == 0 && threadIdx.x < 2)
        claim_node(threadIdx.x ? si : ci, map, nodes, cnt, bitmap);
    if (base < N_EDGES) {  // N_EDGES % 4 == 0
        int4 d = *reinterpret_cast<const int4*>(ei + N_EDGES + base);
        int dv[4] = {d.x, d.y, d.z, d.w};
#pragma unroll
        for (int j = 0; j < 4; j++)
            if (dv[j] == ci || dv[j] == si)
                claim_node(ei[base + j], map, nodes, cnt, bitmap);
    }
}

// ---- 3. slot-CSR of in-edges of marked nodes (bitmap fast-path screen) ----
__global__ __launch_bounds__(256) void k_csr(const int* __restrict__ ei,
                                             const int* __restrict__ et,
                                             const unsigned* __restrict__ bitmap,
                                             const int* __restrict__ map,
                                             int* __restrict__ degs,
                                             unsigned* __restrict__ eslot) {
    int base = (blockIdx.x * 256 + threadIdx.x) * 4;
    if (base < N_EDGES) {
        int4 d = *reinterpret_cast<const int4*>(ei + N_EDGES + base);
        int dv[4] = {d.x, d.y, d.z, d.w};
#pragma unroll
        for (int j = 0; j < 4; j++) {
            int dst = dv[j];
            // 6.25 KB bitmap: L1-resident screen; map (200 KB, L2) touched only on hit
            if ((bitmap[dst >> 5] >> (dst & 31)) & 1u) {
                int m = map[dst];
                if (m >= 0) {
                    int idx = atomicAdd(&degs[m], 1);
                    if (idx < CAP_DEG)
                        eslot[(size_t)m * CAP_DEG + idx] =
                            (unsigned)ei[base + j] | ((unsigned)et[base + j] << 16);
                }
            }
        }
    }
}

// ---- 4. layer-1 fused: aggregate z (all i) + output-column-chunk GEMM ----
// block (slot, jch): writes h1c[slot][jch*30 .. +30) complete (bias + lrelu applied).
__global__ __launch_bounds__(256) void k_zh1(const float* __restrict__ x,
                                             const unsigned* __restrict__ eslot,
                                             const int* __restrict__ degs,
                                             const int* __restrict__ nodes,
                                             const int* __restrict__ cnt,
                                             const float* __restrict__ comp,
                                             const float* __restrict__ basis,
                                             const float* __restrict__ root,
                                             const float* __restrict__ bias,
                                             float* __restrict__ h1c) {
    int slot = blockIdx.x;
    if (slot >= min(cnt[0], CAP_S1)) return;
    int j0 = blockIdx.y * CHUNK;
    int t = threadIdx.x;
    __shared__ float zs[5][DIM];
    __shared__ unsigned els[CAP_DEG];
    __shared__ float cs[N_REL * N_BASIS];
    __shared__ float red[NCH][CHUNK];
    int deg = min(degs[slot], CAP_DEG);
    if (t < N_REL * N_BASIS) cs[t] = comp[t];
    if (t < deg) els[t] = eslot[(size_t)slot * CAP_DEG + t];
    __syncthreads();
    if (t < DIM) {
        float a0 = 0.f, a1 = 0.f, a2 = 0.f, a3 = 0.f;
        int base = 0;
        for (; base + 4 <= deg; base += 4) {
            float xv[4]; int ty[4];
#pragma unroll
            for (int j = 0; j < 4; j++) {
                unsigned p = els[base + j];
                ty[j] = (int)(p >> 16);
                xv[j] = x[(size_t)(p & 0xFFFFu) * DIM + t];
            }
#pragma unroll
            for (int j = 0; j < 4; j++) {
                const float* c = &cs[ty[j] * N_BASIS];
                a0 += c[0] * xv[j]; a1 += c[1] * xv[j];
                a2 += c[2] * xv[j]; a3 += c[3] * xv[j];
            }
        }
        for (; base < deg; base++) {
            unsigned p = els[base];
            const float* c = &cs[(p >> 16) * N_BASIS];
            float xv = x[(size_t)(p & 0xFFFFu) * DIM + t];
            a0 += c[0] * xv; a1 += c[1] * xv; a2 += c[2] * xv; a3 += c[3] * xv;
        }
        zs[0][t] = a0; zs[1][t] = a1; zs[2][t] = a2; zs[3][t] = a3;
        zs[4][t] = x[(size_t)nodes[slot] * DIM + t];
    }
    __syncthreads();
    // GEMM over full i for this j-chunk: thread = (j, ipart)
    if (t < DIM) {
        int j = t % CHUNK, ip = t / CHUNK;   // 30 x 8
        float acc = 0.f;
#pragma unroll 6
        for (int ii = 0; ii < CHUNK; ii++) {
            int i = ip * CHUNK + ii;
            int col = j0 + j;
            acc += zs[0][i] * basis[(size_t)(0 * DIM + i) * DIM + col];
            acc += zs[1][i] * basis[(size_t)(1 * DIM + i) * DIM + col];
            acc += zs[2][i] * basis[(size_t)(2 * DIM + i) * DIM + col];
            acc += zs[3][i] * basis[(size_t)(3 * DIM + i) * DIM + col];
            acc += zs[4][i] * root[(size_t)i * DIM + col];
        }
        red[ip][j] = acc;
    }
    __syncthreads();
    if (t < CHUNK) {
        float s = 0.f;
#pragma unroll
        for (int ip = 0; ip < NCH; ip++) s += red[ip][t];
        s += bias[j0 + t];
        h1c[(size_t)slot * DIM + j0 + t] = lrelu(s);   // layer-0 activation folded in
    }
}

// ---- 5. layer-2 fused + last-block MLP head ----
__global__ __launch_bounds__(256) void k_zh2head(const float* __restrict__ h1c,
                                                 const unsigned* __restrict__ eslot,
                                                 const int* __restrict__ degs,
                                                 const int* __restrict__ map,
                                                 const float* __restrict__ comp2,
                                                 const float* __restrict__ basis2,
                                                 const float* __restrict__ root2,
                                                 const float* __restrict__ bias2,
                                                 const float* __restrict__ W1,
                                                 const float* __restrict__ b1,
                                                 const float* __restrict__ W2,
                                                 const float* __restrict__ b2,
                                                 const int* __restrict__ cip,
                                                 const int* __restrict__ sip,
                                                 float* __restrict__ h2,
                                                 int* __restrict__ done,
                                                 float* __restrict__ out) {
    int bi = blockIdx.x;           // 0..15
    int w = bi >> 3, j0 = (bi & 7) * CHUNK;
    int t = threadIdx.x;
    __shared__ float zs[5][DIM];
    __shared__ unsigned els[CAP_DEG];
    __shared__ int  sslot[CAP_DEG];
    __shared__ float cs[N_REL * N_BASIS];
    __shared__ float red[NCH][CHUNK];
    __shared__ int lastflag;
    int node = w ? sip[0] : cip[0];
    int slot = map[node];
    int deg = (slot >= 0) ? min(degs[slot], CAP_DEG) : 0;
    if (t < N_REL * N_BASIS) cs[t] = comp2[t];
    if (t < deg) {
        unsigned p = eslot[(size_t)slot * CAP_DEG + t];
        els[t] = p;
        sslot[t] = map[p & 0xFFFFu];   // one gather per edge (not per-thread redundant)
    }
    __syncthreads();
    if (t < DIM) {
        float a0 = 0.f, a1 = 0.f, a2 = 0.f, a3 = 0.f;
        int base = 0;
        for (; base + 4 <= deg; base += 4) {
            float hv[4]; int ty[4];
#pragma unroll
            for (int j = 0; j < 4; j++) {
                int ss = sslot[base + j];
                ty[j] = (int)(els[base + j] >> 16);
                hv[j] = (ss >= 0) ? h1c[(size_t)ss * DIM + t] : 0.f;
            }
#pragma unroll
            for (int j = 0; j < 4; j++) {
                const float* c = &cs[ty[j] * N_BASIS];
                a0 += c[0] * hv[j]; a1 += c[1] * hv[j];
                a2 += c[2] * hv[j]; a3 += c[3] * hv[j];
            }
        }
        for (; base < deg; base++) {
            int ss = sslot[base];
            const float* c = &cs[(els[base] >> 16) * N_BASIS];
            float hv = (ss >= 0) ? h1c[(size_t)ss * DIM + t] : 0.f;
            a0 += c[0] * hv; a1 += c[1] * hv; a2 += c[2] * hv; a3 += c[3] * hv;
        }
        zs[0][t] = a0; zs[1][t] = a1; zs[2][t] = a2; zs[3][t] = a3;
        zs[4][t] = (slot >= 0) ? h1c[(size_t)slot * DIM + t] : 0.f;
    }
    __syncthreads();
    if (t < DIM) {
        int j = t % CHUNK, ip = t / CHUNK;
        float acc = 0.f;
#pragma unroll 6
        for (int ii = 0; ii < CHUNK; ii++) {
            int i = ip * CHUNK + ii;
            int col = j0 + j;
            acc += zs[0][i] * basis2[(size_t)(0 * DIM + i) * DIM + col];
            acc += zs[1][i] * basis2[(size_t)(1 * DIM + i) * DIM + col];
            acc += zs[2][i] * basis2[(size_t)(2 * DIM + i) * DIM + col];
            acc += zs[3][i] * basis2[(size_t)(3 * DIM + i) * DIM + col];
            acc += zs[4][i] * root2[(size_t)i * DIM + col];
        }
        red[ip][j] = acc;
    }
    __syncthreads();
    if (t < CHUNK) {
        float s = 0.f;
#pragma unroll
        for (int ip = 0; ip < NCH; ip++) s += red[ip][t];
        h2[w * DIM + j0 + t] = s + bias2[j0 + t];   // last layer: no relu
    }
    // ---- last-block gate (device-scope; cheap, unlike grid.sync) ----
    __threadfence();
    __syncthreads();
    if (t == 0) lastflag = (atomicAdd(done, 1) == 15) ? 1 : 0;
    __syncthreads();
    if (!lastflag) return;
    __threadfence();  // acquire all h2 writes

    // ---- MLP head ----
    __shared__ float cat[2 * DIM];
    __shared__ float part[128][2];
    __shared__ float hid[128];
    if (t < DIM) {
        float hc = h2[t];
        float hs = h2[DIM + t];
        cat[t] = fabsf(hs - hc);
        cat[DIM + t] = hs * hc;
    }
    __syncthreads();
    {
        int r = t >> 1, q = t & 1;
        const float4* wr = reinterpret_cast<const float4*>(W1 + (size_t)r * 2 * DIM) + q * 60;
        const float4* cq = reinterpret_cast<const float4*>(cat) + q * 60;
        float acc = 0.f;
#pragma unroll 6
        for (int k = 0; k < 60; k++) {
            float4 wv = wr[k], cv = cq[k];
            acc += wv.x * cv.x + wv.y * cv.y + wv.z * cv.z + wv.w * cv.w;
        }
        part[r][q] = acc;
    }
    __syncthreads();
    if ((t & 1) == 0) {
        int r = t >> 1;
        float s = part[r][0] + part[r][1] + b1[r];
        hid[r] = lrelu(s) * W2[r];
    }
    __syncthreads();
    if (t < 64) {
        float v = hid[t] + hid[t + 64];
        for (int o = 32; o > 0; o >>= 1) v += __shfl_down(v, o);
        if (t == 0) out[0] = b2[0] + v;
    }
}

// ================= launch: 5 plain dispatches, no memset, no cooperative =================
extern "C" void kernel_launch(void* const* d_in, const int* in_sizes, int n_in,
                              void* d_out, int out_size, void* d_ws, size_t ws_size,
                              hipStream_t stream) {
    const float* x     = (const float*)d_in[0];
    const int*   ei    = (const int*)d_in[1];
    const int*   et    = (const int*)d_in[2];
    const float* comp  = (const float*)d_in[3];
    const float* basis = (const float*)d_in[4];
    const float* root  = (const float*)d_in[5];
    const float* bias  = (const float*)d_in[6];
    const float* W1    = (const float*)d_in[7];
    const float* b1    = (const float*)d_in[8];
    const float* W2    = (const float*)d_in[9];
    const float* b2    = (const float*)d_in[10];
    const int*   cip   = (const int*)d_in[11];
    const int*   sip   = (const int*)d_in[12];
    float* out = (float*)d_out;
    (void)n_in; (void)in_sizes; (void)out_size;

    char* ws = (char*)d_ws;
    if (ws_size < WS_TOTAL) return;

    int*      cnt    = (int*)(ws + WS_CNT);
    int*      done   = (int*)(ws + WS_DONE);
    int*      degs   = (int*)(ws + WS_DEGS);
    unsigned* bitmap = (unsigned*)(ws + WS_BITMAP);
    int*      map    = (int*)(ws + WS_MAP);
    int*      nodes  = (int*)(ws + WS_NODES);
    unsigned* eslot  = (unsigned*)(ws + WS_ESLOT);
    float*    h1c    = (float*)(ws + WS_H1C);
    float*    h2     = (float*)(ws + WS_H2);

    const float* comp2  = comp  + N_REL * N_BASIS;
    const float* basis2 = basis + (size_t)N_BASIS * DIM * DIM;
    const float* root2  = root  + (size_t)DIM * DIM;
    const float* bias2  = bias  + DIM;

    int egrid4 = (N_EDGES / 4 + 255) / 256;  // 1563

    k_init<<<256, 256, 0, stream>>>(cnt, done, degs, map, bitmap);
    k_mark<<<egrid4, 256, 0, stream>>>(ei, cip, sip, map, nodes, cnt, bitmap);
    k_csr<<<egrid4, 256, 0, stream>>>(ei, et, bitmap, map, degs, eslot);
    k_zh1<<<dim3(CAP_S1, NCH), 256, 0, stream>>>(x, eslot, degs, nodes, cnt,
                                                 comp, basis, root, bias, h1c);
    k_zh2head<<<16, 256, 0, stream>>>(h1c, eslot, degs, map, comp2, basis2, root2,
                                      bias2, W1, b1, W2, b2, cip, sip, h2, done, out);
}